// Round 4
// baseline (1198.230 us; speedup 1.0000x reference)
//
#include <hip/hip_runtime.h>

// LaplacianKnn:  y'[i] = a*y[i] + sum_j w_e * y[nbr_e],  out = dot(x, y_nu)
//   w_e = b*t_e/s_i, t_e = exp(-dist_e/eps)*Dinv[nbr_e], s_i = row-sum(t)
//   a = 4/eps + 2nu/k^2 + 10,  b = -4/eps
// R4 = R3 with ext_vector_type for __builtin_nontemporal_load (HIP_vector_type
// structs are rejected by the builtin). 4 edges/thread: int4/float4 nt streams
// + 4 independent 4B gathers in flight vs 1 (gather-latency bound per R2
// counters: 245us, 11% HBM, 12% VALU, 0 conflicts). y gather array = 4 MB ->
// L2-resident per XCD; nt on all 128MB-class streams so they don't evict it.

typedef float __attribute__((ext_vector_type(4))) floatx4;
typedef int   __attribute__((ext_vector_type(4))) intx4;

static constexpr int BLOCK = 256;  // 256 thr * 4 edges = 1024 edges = 32 rows/block

__global__ __launch_bounds__(256) void dinv_kernel(
    const float* __restrict__ dist, const float* __restrict__ eps_p,
    float* __restrict__ Dinv, int n_edges) {
  int t = blockIdx.x * BLOCK + threadIdx.x;
  int e4 = t << 2;
  float inv_eps = 1.0f / eps_p[0];
  float s = 0.0f;
  if (e4 < n_edges) {
    floatx4 d = __builtin_nontemporal_load((const floatx4*)(dist + e4));
    s = __expf(-d.x * inv_eps) + __expf(-d.y * inv_eps) +
        __expf(-d.z * inv_eps) + __expf(-d.w * inv_eps);
  }
  #pragma unroll
  for (int off = 4; off > 0; off >>= 1) s += __shfl_down(s, off, 8);
  if ((t & 7) == 0 && e4 < n_edges) Dinv[t >> 3] = 1.0f / s;
}

__global__ __launch_bounds__(256) void wcoef_kernel(
    const float* __restrict__ dist, const int* __restrict__ nbr,
    const float* __restrict__ Dinv, const float* __restrict__ eps_p,
    float* __restrict__ wout, int n_edges) {
  int t = blockIdx.x * BLOCK + threadIdx.x;
  int e4 = t << 2;
  if (e4 >= n_edges) return;
  float inv_eps = 1.0f / eps_p[0];
  float b = -4.0f * inv_eps;
  intx4   j = __builtin_nontemporal_load((const intx4*)(nbr + e4));
  floatx4 d = __builtin_nontemporal_load((const floatx4*)(dist + e4));
  // 4 independent L2-resident gathers in flight
  float q0 = Dinv[j.x], q1 = Dinv[j.y], q2 = Dinv[j.z], q3 = Dinv[j.w];
  float t0 = __expf(-d.x * inv_eps) * q0;
  float t1 = __expf(-d.y * inv_eps) * q1;
  float t2 = __expf(-d.z * inv_eps) * q2;
  float t3 = __expf(-d.w * inv_eps) * q3;
  float s = t0 + t1 + t2 + t3;
  #pragma unroll
  for (int off = 1; off < 8; off <<= 1) s += __shfl_xor(s, off, 8);  // all 8 lanes get row sum
  float bs = b / s;
  floatx4 w = {t0 * bs, t1 * bs, t2 * bs, t3 * bs};
  __builtin_nontemporal_store(w, (floatx4*)(wout + e4));
}

template <bool LAST>
__global__ __launch_bounds__(256) void sweep_kernel(
    const int* __restrict__ nbr, const float* __restrict__ w,
    const float* __restrict__ yin, float* __restrict__ yout,
    const float* __restrict__ x,
    const float* __restrict__ eps_p, const float* __restrict__ k_p,
    const int* __restrict__ nu_p,
    float* __restrict__ out, int n_edges) {
  __shared__ float bsum;
  if (LAST) { if (threadIdx.x == 0) bsum = 0.0f; __syncthreads(); }
  int t = blockIdx.x * BLOCK + threadIdx.x;
  int e4 = t << 2;
  float g = 0.0f;
  float acc = 0.0f;
  if (e4 < n_edges) {
    intx4   j  = __builtin_nontemporal_load((const intx4*)(nbr + e4));
    floatx4 wv = __builtin_nontemporal_load((const floatx4*)(w + e4));
    // 4 independent gathers from the 4 MB L2-resident y array
    float y0 = yin[j.x], y1 = yin[j.y], y2 = yin[j.z], y3 = yin[j.w];
    g = wv.x * y0 + wv.y * y1 + wv.z * y2 + wv.w * y3;
  }
  #pragma unroll
  for (int off = 4; off > 0; off >>= 1) g += __shfl_down(g, off, 8);
  if ((t & 7) == 0 && e4 < n_edges) {
    int node = t >> 3;
    float inv_eps = 1.0f / eps_p[0];
    float kk = k_p[0];
    float a = 4.0f * inv_eps + 2.0f * (float)nu_p[0] / (kk * kk) + 10.0f;
    float ynew = a * yin[node] + g;  // w already folds b and 1/s
    if (LAST) acc = x[node] * ynew;
    else __builtin_nontemporal_store(ynew, yout + node);
  }
  if (LAST) {
    // leaders sit at lanes 0,8,...,56: collapse them into lane 0 of the wave
    #pragma unroll
    for (int off = 32; off >= 8; off >>= 1) acc += __shfl_down(acc, off, 64);
    if ((threadIdx.x & 63) == 0) atomicAdd(&bsum, acc);
    __syncthreads();
    if (threadIdx.x == 0) atomicAdd(out, bsum);
  }
}

extern "C" void kernel_launch(void* const* d_in, const int* in_sizes, int n_in,
                              void* d_out, int out_size, void* d_ws, size_t ws_size,
                              hipStream_t stream) {
  const float* x     = (const float*)d_in[0];
  const int*   nbr   = (const int*)d_in[1];
  const float* dist  = (const float*)d_in[2];
  const float* eps_p = (const float*)d_in[3];
  const float* k_p   = (const float*)d_in[4];
  const int*   nu_p  = (const int*)d_in[5];
  float* out = (float*)d_out;

  int n  = in_sizes[0];   // 1,000,000 nodes
  int ne = in_sizes[1];   // 32,000,000 edges

  float* w    = (float*)d_ws;  // [ne]
  float* Dinv = w + ne;        // [n]
  float* y0   = Dinv + n;      // [n]
  float* y1   = y0 + n;        // [n]

  (void)hipMemsetAsync(d_out, 0, sizeof(float), stream);

  int grid = (ne + BLOCK * 4 - 1) / (BLOCK * 4);
  dinv_kernel<<<grid, BLOCK, 0, stream>>>(dist, eps_p, Dinv, ne);
  wcoef_kernel<<<grid, BLOCK, 0, stream>>>(dist, nbr, Dinv, eps_p, w, ne);
  sweep_kernel<false><<<grid, BLOCK, 0, stream>>>(nbr, w, x,  y0, x, eps_p, k_p, nu_p, out, ne);
  sweep_kernel<false><<<grid, BLOCK, 0, stream>>>(nbr, w, y0, y1, x, eps_p, k_p, nu_p, out, ne);
  sweep_kernel<true ><<<grid, BLOCK, 0, stream>>>(nbr, w, y1, nullptr, x, eps_p, k_p, nu_p, out, ne);
}

// Round 5
// 1067.264 us; speedup vs baseline: 1.1227x; 1.1227x over previous
//
#include <hip/hip_runtime.h>

// LaplacianKnn:  y'[i] = a*y[i] + b * sum_j m_e * y[nbr_e],  out = dot(x, y_nu)
//   m_e = t_e/s_i, t_e = exp(-dist_e/eps)*Dinv[nbr_e], s_i = row-sum(t), sum_e m_e = 1
//   a = 4/eps + 2nu/k^2 + 10,  b = -4/eps
// R5: R2-proven sweep shape (1 edge/thread, PLAIN gather + PLAIN y store so y
// stays L2-resident — R4 showed nt on the y path costs 1.7x) with edges packed
// to 4B: (nbr<<12)|round(4096*m). Halves sweep stream traffic 256->128MB.
// Quantization: |err| per sweep ~4e-4 relative, tolerance is ~2%.

typedef float __attribute__((ext_vector_type(4))) floatx4;
typedef int   __attribute__((ext_vector_type(4))) intx4;
typedef unsigned int uint32;

static constexpr int BLOCK = 256;

// ---- pass 1: Dinv[i] = 1 / sum_j exp(-dist[i][j]/eps)   (4 edges/thread) ----
__global__ __launch_bounds__(256) void dinv_kernel(
    const float* __restrict__ dist, const float* __restrict__ eps_p,
    float* __restrict__ Dinv, int n_edges) {
  int t = blockIdx.x * BLOCK + threadIdx.x;
  int e4 = t << 2;
  if (e4 >= n_edges) return;
  float inv_eps = 1.0f / eps_p[0];
  floatx4 d = __builtin_nontemporal_load((const floatx4*)(dist + e4));
  float s = __expf(-d.x * inv_eps) + __expf(-d.y * inv_eps) +
            __expf(-d.z * inv_eps) + __expf(-d.w * inv_eps);
  #pragma unroll
  for (int off = 4; off > 0; off >>= 1) s += __shfl_down(s, off, 8);
  if ((t & 7) == 0) Dinv[t >> 3] = 1.0f / s;
}

// ---- pass 2: pack edge -> (nbr<<12) | round(4096 * t_e / s_i)  ----
// R2 wcoef shape: 1 edge/thread, butterfly over the 32-lane row.
__global__ __launch_bounds__(256) void pack_kernel(
    const float* __restrict__ dist, const int* __restrict__ nbr,
    const float* __restrict__ Dinv, const float* __restrict__ eps_p,
    uint32* __restrict__ pk, int n_edges) {
  int e = blockIdx.x * BLOCK + threadIdx.x;
  if (e >= n_edges) return;
  float inv_eps = 1.0f / eps_p[0];
  int j = __builtin_nontemporal_load(nbr + e);
  float t = __expf(-__builtin_nontemporal_load(dist + e) * inv_eps) * Dinv[j];
  float s = t;
  #pragma unroll
  for (int off = 1; off < 32; off <<= 1) s += __shfl_xor(s, off, 32);
  uint32 mq = (uint32)__float2uint_rn(t * (4096.0f / s));
  if (mq > 4095u) mq = 4095u;
  __builtin_nontemporal_store(((uint32)j << 12) | mq, pk + e);
}

// ---- sweeps: 1 edge/thread, grid-stride (LAST uses 1/8 grid for atomics) ----
template <bool LAST>
__global__ __launch_bounds__(256) void sweep_kernel(
    const uint32* __restrict__ pk,
    const float* __restrict__ yin, float* __restrict__ yout,
    const float* __restrict__ x,
    const float* __restrict__ eps_p, const float* __restrict__ k_p,
    const int* __restrict__ nu_p,
    float* __restrict__ out, int n_edges) {
  __shared__ float bsum;
  if (LAST) { if (threadIdx.x == 0) bsum = 0.0f; __syncthreads(); }
  float inv_eps = 1.0f / eps_p[0];
  float kk = k_p[0];
  float a  = 4.0f * inv_eps + 2.0f * (float)nu_p[0] / (kk * kk) + 10.0f;
  float bq = -4.0f * inv_eps * (1.0f / 4096.0f);
  int stride = gridDim.x * BLOCK;
  for (int e = blockIdx.x * BLOCK + threadIdx.x; e < n_edges; e += stride) {
    uint32 p = __builtin_nontemporal_load(pk + e);   // single 4B stream load/edge
    float g = (float)(p & 0xFFFu) * yin[p >> 12];    // PLAIN gather, L2-resident 4MB
    #pragma unroll
    for (int off = 16; off > 0; off >>= 1) g += __shfl_down(g, off, 32);
    if ((threadIdx.x & 31) == 0) {
      int node = e >> 5;
      float ynew = a * yin[node] + bq * g;
      if (LAST) atomicAdd(&bsum, x[node] * ynew);
      else yout[node] = ynew;        // PLAIN store: keep y hot in L2 for next sweep
    }
  }
  if (LAST) { __syncthreads(); if (threadIdx.x == 0) atomicAdd(out, bsum); }
}

extern "C" void kernel_launch(void* const* d_in, const int* in_sizes, int n_in,
                              void* d_out, int out_size, void* d_ws, size_t ws_size,
                              hipStream_t stream) {
  const float* x     = (const float*)d_in[0];
  const int*   nbr   = (const int*)d_in[1];
  const float* dist  = (const float*)d_in[2];
  const float* eps_p = (const float*)d_in[3];
  const float* k_p   = (const float*)d_in[4];
  const int*   nu_p  = (const int*)d_in[5];
  float* out = (float*)d_out;

  int n  = in_sizes[0];   // 1,000,000 nodes  (< 2^20 -> 20-bit index fits)
  int ne = in_sizes[1];   // 32,000,000 edges

  uint32* pk  = (uint32*)d_ws;          // [ne]  packed edges
  float* Dinv = (float*)(pk + ne);      // [n]
  float* y0   = Dinv + n;               // [n]
  float* y1   = y0 + n;                 // [n]

  (void)hipMemsetAsync(d_out, 0, sizeof(float), stream);

  int gridE = (ne + BLOCK - 1) / BLOCK;            // 1 edge/thread
  int grid4 = (ne + BLOCK * 4 - 1) / (BLOCK * 4);  // 4 edges/thread
  dinv_kernel<<<grid4, BLOCK, 0, stream>>>(dist, eps_p, Dinv, ne);
  pack_kernel<<<gridE, BLOCK, 0, stream>>>(dist, nbr, Dinv, eps_p, pk, ne);
  sweep_kernel<false><<<gridE, BLOCK, 0, stream>>>(pk, x,  y0, x, eps_p, k_p, nu_p, out, ne);
  sweep_kernel<false><<<gridE, BLOCK, 0, stream>>>(pk, y0, y1, x, eps_p, k_p, nu_p, out, ne);
  sweep_kernel<true ><<<gridE / 8, BLOCK, 0, stream>>>(pk, y1, nullptr, x, eps_p, k_p, nu_p, out, ne);
}

// Round 6
// 890.996 us; speedup vs baseline: 1.3448x; 1.1978x over previous
//
#include <hip/hip_runtime.h>
#include <hip/hip_fp16.h>

// LaplacianKnn:  y'[i] = a*y[i] + b * sum_j m_e * y[nbr_e],  out = dot(x, y_nu)
//   m_e = t_e/s_i, t_e = exp(-dist_e/eps)*Dinv[nbr_e], s_i = row-sum(t)
//   a = 4/eps + 2nu/k^2 + 10,  b = -4/eps
// R6: total time == (#random-gather passes) x ~230us wall (R5 evidence: halving
// stream bytes moved sweep 245->237us; gathers are L2-hit and request-limited).
// So cut a pass: fuse pack into sweep1. Sweep1 gathers z4[j]=half2(Dinv,x)
// (4B from a 4MB array -> same request profile as a sweep), computes t_e,
// row-sum, y1, AND writes the packed edges (nbr<<12|12-bit m) for sweeps 2-3.
// Passes: dinv(coalesced) + fsweep + 2 sweeps = 3 gather passes instead of 4.

typedef float __attribute__((ext_vector_type(4))) floatx4;
typedef unsigned int uint32;

static constexpr int BLOCK = 256;

// ---- pass 1 (coalesced only): z4[i] = half2(1/sum_j exp(-d/eps), x[i]) ----
__global__ __launch_bounds__(256) void dinv_kernel(
    const float* __restrict__ dist, const float* __restrict__ x,
    const float* __restrict__ eps_p,
    __half2* __restrict__ z4, int n_edges) {
  int t = blockIdx.x * BLOCK + threadIdx.x;
  int e4 = t << 2;
  if (e4 >= n_edges) return;
  float inv_eps = 1.0f / eps_p[0];
  floatx4 d = __builtin_nontemporal_load((const floatx4*)(dist + e4));
  float s = __expf(-d.x * inv_eps) + __expf(-d.y * inv_eps) +
            __expf(-d.z * inv_eps) + __expf(-d.w * inv_eps);
  #pragma unroll
  for (int off = 4; off > 0; off >>= 1) s += __shfl_down(s, off, 8);
  if ((t & 7) == 0) {
    int node = t >> 3;
    z4[node] = __halves2half2(__float2half(1.0f / s), __float2half(x[node]));
  }
}

// ---- pass 2 (fused pack + sweep 1): one 4B gather/edge from 4MB z4 ----
__global__ __launch_bounds__(256) void fsweep_kernel(
    const float* __restrict__ dist, const int* __restrict__ nbr,
    const __half2* __restrict__ z4,
    const float* __restrict__ x, const float* __restrict__ eps_p,
    const float* __restrict__ k_p, const int* __restrict__ nu_p,
    uint32* __restrict__ pk, float* __restrict__ yout, int n_edges) {
  int e = blockIdx.x * BLOCK + threadIdx.x;
  if (e >= n_edges) return;
  float inv_eps = 1.0f / eps_p[0];
  int j = __builtin_nontemporal_load(nbr + e);
  float d = __builtin_nontemporal_load(dist + e);
  __half2 z = z4[j];                       // PLAIN gather, L2-resident 4MB
  float t = __expf(-d * inv_eps) * __low2float(z);   // t_e = exp * Dinv[j]
  float g = t * __high2float(z);                     // t_e * x[j]
  float s = t;
  #pragma unroll
  for (int off = 1; off < 32; off <<= 1) s += __shfl_xor(s, off, 32);  // row sum, all lanes
  // emit packed edge for sweeps 2-3
  uint32 mq = (uint32)__float2uint_rn(t * (4096.0f / s));
  if (mq > 4095u) mq = 4095u;
  __builtin_nontemporal_store(((uint32)j << 12) | mq, pk + e);
  // y1[i] = a*x[i] + b*g/s  (leader)
  #pragma unroll
  for (int off = 16; off > 0; off >>= 1) g += __shfl_down(g, off, 32);
  if ((threadIdx.x & 31) == 0) {
    int node = e >> 5;
    float kk = k_p[0];
    float a = 4.0f * inv_eps + 2.0f * (float)nu_p[0] / (kk * kk) + 10.0f;
    float b = -4.0f * inv_eps;
    yout[node] = a * x[node] + b * g / s;   // PLAIN store: keep y hot in L2
  }
}

// ---- sweeps 2,3: 1 edge/thread, grid-stride (LAST uses 1/8 grid) ----
template <bool LAST>
__global__ __launch_bounds__(256) void sweep_kernel(
    const uint32* __restrict__ pk,
    const float* __restrict__ yin, float* __restrict__ yout,
    const float* __restrict__ x,
    const float* __restrict__ eps_p, const float* __restrict__ k_p,
    const int* __restrict__ nu_p,
    float* __restrict__ out, int n_edges) {
  __shared__ float bsum;
  if (LAST) { if (threadIdx.x == 0) bsum = 0.0f; __syncthreads(); }
  float inv_eps = 1.0f / eps_p[0];
  float kk = k_p[0];
  float a  = 4.0f * inv_eps + 2.0f * (float)nu_p[0] / (kk * kk) + 10.0f;
  float bq = -4.0f * inv_eps * (1.0f / 4096.0f);
  int stride = gridDim.x * BLOCK;
  for (int e = blockIdx.x * BLOCK + threadIdx.x; e < n_edges; e += stride) {
    uint32 p = __builtin_nontemporal_load(pk + e);   // single 4B stream load/edge
    float g = (float)(p & 0xFFFu) * yin[p >> 12];    // PLAIN gather, L2-resident 4MB
    #pragma unroll
    for (int off = 16; off > 0; off >>= 1) g += __shfl_down(g, off, 32);
    if ((threadIdx.x & 31) == 0) {
      int node = e >> 5;
      float ynew = a * yin[node] + bq * g;
      if (LAST) atomicAdd(&bsum, x[node] * ynew);
      else yout[node] = ynew;        // PLAIN store: keep y hot in L2
    }
  }
  if (LAST) { __syncthreads(); if (threadIdx.x == 0) atomicAdd(out, bsum); }
}

extern "C" void kernel_launch(void* const* d_in, const int* in_sizes, int n_in,
                              void* d_out, int out_size, void* d_ws, size_t ws_size,
                              hipStream_t stream) {
  const float* x     = (const float*)d_in[0];
  const int*   nbr   = (const int*)d_in[1];
  const float* dist  = (const float*)d_in[2];
  const float* eps_p = (const float*)d_in[3];
  const float* k_p   = (const float*)d_in[4];
  const int*   nu_p  = (const int*)d_in[5];
  float* out = (float*)d_out;

  int n  = in_sizes[0];   // 1,000,000 nodes  (< 2^20 -> 20-bit index fits)
  int ne = in_sizes[1];   // 32,000,000 edges

  uint32* pk   = (uint32*)d_ws;         // [ne]  packed edges
  __half2* z4  = (__half2*)(pk + ne);   // [n]   (Dinv, x) in f16
  float* y1    = (float*)(z4 + n);      // [n]
  float* y2    = y1 + n;                // [n]

  (void)hipMemsetAsync(d_out, 0, sizeof(float), stream);

  int gridE = (ne + BLOCK - 1) / BLOCK;            // 1 edge/thread
  int grid4 = (ne + BLOCK * 4 - 1) / (BLOCK * 4);  // 4 edges/thread
  dinv_kernel<<<grid4, BLOCK, 0, stream>>>(dist, x, eps_p, z4, ne);
  fsweep_kernel<<<gridE, BLOCK, 0, stream>>>(dist, nbr, z4, x, eps_p, k_p, nu_p, pk, y1, ne);
  sweep_kernel<false><<<gridE, BLOCK, 0, stream>>>(pk, y1, y2, x, eps_p, k_p, nu_p, out, ne);
  sweep_kernel<true ><<<gridE / 8, BLOCK, 0, stream>>>(pk, y2, nullptr, x, eps_p, k_p, nu_p, out, ne);
}